// Round 1
// baseline (708.304 us; speedup 1.0000x reference)
//
#include <hip/hip_runtime.h>
#include <math.h>

#define NB 4
#define CH 256
#define NHEADS 4
#define HC 64
#define NT 2304   // 48*48

// ---------------------------------------------------------------------------
// Generic channel-mixing GEMM: Y[b][o][n] = sum_c W[o][c] * X[b][c][n] + bias[o]
// M=K=256, Ncols=2304 per batch. grid (NT/64, CH/64, NB), block 256.
// BM=BN=64, BK=16, 4x4 microtile per thread.
// ---------------------------------------------------------------------------
__global__ __launch_bounds__(256) void gemm_bias_f32(
    const float* __restrict__ W, const float* __restrict__ bias,
    const float* __restrict__ X, float* __restrict__ Y)
{
    __shared__ float As[16][68];   // A transposed: As[k][m], pad 68 for banks+align
    __shared__ float Bs[16][64];   // Bs[k][n]

    const int t  = threadIdx.x;
    const int n0 = blockIdx.x * 64;
    const int m0 = blockIdx.y * 64;
    const size_t boff = (size_t)blockIdx.z * CH * NT;
    const float* Xb = X + boff;
    float* Yb = Y + boff;

    const int tm = t >> 4, tn = t & 15;
    float acc[4][4] = {};

    for (int k0 = 0; k0 < CH; k0 += 16) {
        {
            // A tile 64m x 16k -> transposed into LDS
            const int m  = t >> 2;
            const int kq = (t & 3) << 2;
            const float4 a = *reinterpret_cast<const float4*>(
                &W[(size_t)(m0 + m) * CH + k0 + kq]);
            As[kq + 0][m] = a.x; As[kq + 1][m] = a.y;
            As[kq + 2][m] = a.z; As[kq + 3][m] = a.w;
            // B tile 16k x 64n
            const int kr = t >> 4;
            const int n4 = (t & 15) << 2;
            *reinterpret_cast<float4*>(&Bs[kr][n4]) =
                *reinterpret_cast<const float4*>(
                    &Xb[(size_t)(k0 + kr) * NT + n0 + n4]);
        }
        __syncthreads();
#pragma unroll
        for (int kk = 0; kk < 16; ++kk) {
            const float4 av = *reinterpret_cast<const float4*>(&As[kk][tm << 2]);
            const float4 bv = *reinterpret_cast<const float4*>(&Bs[kk][tn << 2]);
            const float a4[4] = {av.x, av.y, av.z, av.w};
            const float b4[4] = {bv.x, bv.y, bv.z, bv.w};
#pragma unroll
            for (int i = 0; i < 4; ++i)
#pragma unroll
                for (int j = 0; j < 4; ++j)
                    acc[i][j] = fmaf(a4[i], b4[j], acc[i][j]);
        }
        __syncthreads();
    }

#pragma unroll
    for (int i = 0; i < 4; ++i) {
        const int m = m0 + (tm << 2) + i;
        const float bs = bias[m];
        float4 o = {acc[i][0] + bs, acc[i][1] + bs,
                    acc[i][2] + bs, acc[i][3] + bs};
        *reinterpret_cast<float4*>(&Yb[(size_t)m * NT + n0 + (tn << 2)]) = o;
    }
}

// ---------------------------------------------------------------------------
// Fused flash-style attention per (b, head):
//   dots[n,m] = sum_c K[c,n] Q[c,m]; softmax over n (keys); O[c,m] = V P.
// grid (NT/64 q-tiles, NHEADS, NB), block 256. Q-tile resident, 64-key chunks.
// LDS: Qs 16KB + KS(K then S, unioned) 16KB + Vt 16KB + stats = 49.9KB.
// ---------------------------------------------------------------------------
__global__ __launch_bounds__(256) void attn_fused_f32(
    const float* __restrict__ Kbuf, const float* __restrict__ Qbuf,
    const float* __restrict__ Vbuf, float* __restrict__ Obuf)
{
    __shared__ float Qs[64 * 64];   // [c][m]
    __shared__ float KS[64 * 64];   // phase A: K as [c][k]; phase B: S/P as [k][m]
    __shared__ float Vt[64 * 64];   // V transposed: [k][c]
    __shared__ float Ml[64], Ll[64], Fc[64];

    const int t  = threadIdx.x;
    const int m0 = blockIdx.x * 64;
    const size_t base = ((size_t)blockIdx.z * CH + (size_t)blockIdx.y * HC) * NT;
    const float* Kg = Kbuf + base;
    const float* Qg = Qbuf + base;
    const float* Vg = Vbuf + base;

    const int tlo = t & 15;   // QK: key group (4 keys); PV: channel group (4 ch)
    const int thi = t >> 4;   // query group (4 queries), same in both phases

    // load resident Q tile [64c][64m]
#pragma unroll
    for (int i = 0; i < 4; ++i) {
        const int lin = t + i * 256;
        const int c   = lin >> 4;
        const int m4  = (lin & 15) << 2;
        *reinterpret_cast<float4*>(&Qs[c * 64 + m4]) =
            *reinterpret_cast<const float4*>(&Qg[(size_t)c * NT + m0 + m4]);
    }
    if (t < 64) { Ml[t] = -3.0e38f; Ll[t] = 0.0f; }

    float acc[4][4] = {};
    __syncthreads();

    for (int kc = 0; kc < NT; kc += 64) {
        // stage K chunk [64c][64k] and V chunk transposed [64k][64c]
#pragma unroll
        for (int i = 0; i < 4; ++i) {
            const int lin = t + i * 256;
            const int c   = lin >> 4;
            const int k4  = (lin & 15) << 2;
            *reinterpret_cast<float4*>(&KS[c * 64 + k4]) =
                *reinterpret_cast<const float4*>(&Kg[(size_t)c * NT + kc + k4]);
            const float4 vv = *reinterpret_cast<const float4*>(
                &Vg[(size_t)c * NT + kc + k4]);
            Vt[(k4 + 0) * 64 + c] = vv.x;
            Vt[(k4 + 1) * 64 + c] = vv.y;
            Vt[(k4 + 2) * 64 + c] = vv.z;
            Vt[(k4 + 3) * 64 + c] = vv.w;
        }
        __syncthreads();

        // QK^T: s[i][j] = sum_c K[c][tlo*4+i] * Q[c][thi*4+j]
        float s[4][4] = {};
#pragma unroll 4
        for (int c = 0; c < 64; ++c) {
            const float4 kv = *reinterpret_cast<const float4*>(&KS[c * 64 + (tlo << 2)]);
            const float4 qv = *reinterpret_cast<const float4*>(&Qs[c * 64 + (thi << 2)]);
            const float k4[4] = {kv.x, kv.y, kv.z, kv.w};
            const float q4[4] = {qv.x, qv.y, qv.z, qv.w};
#pragma unroll
            for (int i = 0; i < 4; ++i)
#pragma unroll
                for (int j = 0; j < 4; ++j)
                    s[i][j] = fmaf(k4[i], q4[j], s[i][j]);
        }
        __syncthreads();   // all lanes done reading K -> KS reusable for S

        // write S as [k][m] into the K buffer
#pragma unroll
        for (int i = 0; i < 4; ++i)
#pragma unroll
            for (int j = 0; j < 4; ++j)
                KS[(((tlo << 2) + i) << 6) + (thi << 2) + j] = s[i][j];
        __syncthreads();

        // online softmax over the 64-key chunk (wave 0, one column per lane)
        if (t < 64) {
            float cm = -3.0e38f;
#pragma unroll 8
            for (int k = 0; k < 64; ++k) cm = fmaxf(cm, KS[(k << 6) + t]);
            const float mOld = Ml[t];
            const float mNew = fmaxf(mOld, cm);
            const float fac  = __expf(mOld - mNew);
            float sum = 0.0f;
#pragma unroll 8
            for (int k = 0; k < 64; ++k) {
                const float p = __expf(KS[(k << 6) + t] - mNew);
                KS[(k << 6) + t] = p;
                sum += p;
            }
            Ll[t] = Ll[t] * fac + sum;
            Ml[t] = mNew;
            Fc[t] = fac;
        }
        __syncthreads();

        // rescale accumulator, then O += V * P
        float f4[4];
#pragma unroll
        for (int j = 0; j < 4; ++j) f4[j] = Fc[(thi << 2) + j];
#pragma unroll
        for (int i = 0; i < 4; ++i)
#pragma unroll
            for (int j = 0; j < 4; ++j) acc[i][j] *= f4[j];

#pragma unroll 4
        for (int k = 0; k < 64; ++k) {
            const float4 vv = *reinterpret_cast<const float4*>(&Vt[(k << 6) + (tlo << 2)]);
            const float4 pv = *reinterpret_cast<const float4*>(&KS[(k << 6) + (thi << 2)]);
            const float v4[4] = {vv.x, vv.y, vv.z, vv.w};
            const float p4[4] = {pv.x, pv.y, pv.z, pv.w};
#pragma unroll
            for (int i = 0; i < 4; ++i)
#pragma unroll
                for (int j = 0; j < 4; ++j)
                    acc[i][j] = fmaf(v4[i], p4[j], acc[i][j]);
        }
        __syncthreads();   // protect KS/Vt before next chunk's staging
    }

    // epilogue: divide by softmax denominator, store mid-output [c][m]
    float invL[4];
#pragma unroll
    for (int j = 0; j < 4; ++j) invL[j] = 1.0f / Ll[(thi << 2) + j];
    float* Ob = Obuf + base;
#pragma unroll
    for (int i = 0; i < 4; ++i) {
        float4 o = {acc[i][0] * invL[0], acc[i][1] * invL[1],
                    acc[i][2] * invL[2], acc[i][3] * invL[3]};
        *reinterpret_cast<float4*>(
            &Ob[(size_t)((tlo << 2) + i) * NT + m0 + (thi << 2)]) = o;
    }
}

// ---------------------------------------------------------------------------
extern "C" void kernel_launch(void* const* d_in, const int* in_sizes, int n_in,
                              void* d_out, int out_size, void* d_ws, size_t ws_size,
                              hipStream_t stream) {
    (void)in_sizes; (void)n_in; (void)out_size; (void)ws_size;
    const float* x  = (const float*)d_in[0];
    const float* wk = (const float*)d_in[1];
    const float* bk = (const float*)d_in[2];
    const float* wq = (const float*)d_in[3];
    const float* bq = (const float*)d_in[4];
    const float* wv = (const float*)d_in[5];
    const float* bv = (const float*)d_in[6];
    const float* wo = (const float*)d_in[7];
    const float* bo = (const float*)d_in[8];
    float* out = (float*)d_out;

    float* ws = (float*)d_ws;
    const size_t SZ = (size_t)NB * CH * NT;   // 2,359,296 floats per tensor
    float* kb = ws;
    float* qb = ws + SZ;
    float* vb = ws + 2 * SZ;
    float* ob = ws + 3 * SZ;                  // total 37.7 MB of d_ws

    dim3 gg(NT / 64, CH / 64, NB);            // (36, 4, 4)
    gemm_bias_f32<<<gg, 256, 0, stream>>>(wk, bk, x, kb);
    gemm_bias_f32<<<gg, 256, 0, stream>>>(wq, bq, x, qb);
    gemm_bias_f32<<<gg, 256, 0, stream>>>(wv, bv, x, vb);

    dim3 ga(NT / 64, NHEADS, NB);             // (36, 4, 4)
    attn_fused_f32<<<ga, 256, 0, stream>>>(kb, qb, vb, ob);

    gemm_bias_f32<<<gg, 256, 0, stream>>>(wo, bo, ob, out);
}

// Round 3
// 260.151 us; speedup vs baseline: 2.7227x; 2.7227x over previous
//
#include <hip/hip_runtime.h>
#include <math.h>

#define NB 4
#define CH 256
#define NHEADS 4
#define HC 64
#define NT 2304   // 48*48

typedef _Float16 f16;
typedef _Float16 f16x4 __attribute__((ext_vector_type(4)));
typedef _Float16 f16x8 __attribute__((ext_vector_type(8)));
typedef float f32x4 __attribute__((ext_vector_type(4)));

#define MFMA16(a, b, c) __builtin_amdgcn_mfma_f32_16x16x32_f16(a, b, c, 0, 0, 0)

// ---------------------------------------------------------------------------
// x [b][c][n] f32  ->  Xt [b][n][c] f16   (so GEMM B-frags read contiguous c)
// grid (36, 4, 4) = (ntile, ctile, b), block 256.
// ---------------------------------------------------------------------------
__global__ __launch_bounds__(256) void xpose_f32_to_f16(
    const float* __restrict__ X, f16* __restrict__ Xt)
{
    __shared__ f16 T[64][68];   // [c][n], pad 68 halves
    const int t = threadIdx.x;
    const int n0 = blockIdx.x * 64, c0 = blockIdx.y * 64, b = blockIdx.z;

#pragma unroll
    for (int i = 0; i < 4; ++i) {
        const int lin = i * 256 + t;
        const int c = lin >> 4, n4 = (lin & 15) << 2;
        const float4 v = *reinterpret_cast<const float4*>(
            &X[((size_t)(b * CH + c0 + c)) * NT + n0 + n4]);
        f16x4 hv = {(f16)v.x, (f16)v.y, (f16)v.z, (f16)v.w};
        *reinterpret_cast<f16x4*>(&T[c][n4]) = hv;
    }
    __syncthreads();
    {
        const int n = t >> 2, cs = (t & 3) << 4;
        f16x8 o0, o1;
#pragma unroll
        for (int k = 0; k < 8; ++k) o0[k] = T[cs + k][n];
#pragma unroll
        for (int k = 0; k < 8; ++k) o1[k] = T[cs + 8 + k][n];
        f16* dst = &Xt[((size_t)(b * NT + n0 + n)) * CH + c0 + cs];
        *reinterpret_cast<f16x8*>(dst) = o0;
        *reinterpret_cast<f16x8*>(dst + 8) = o1;
    }
}

// ---------------------------------------------------------------------------
// Fused K/Q/V projection, MFMA f16.  Y = W @ X + bias.
// grid (36, 12, 4): x = ntile(64n), y: sel = y>>2 (0=K,1=Q,2=V), h = y&3 (o-tile),
// z = batch. Block 256 = 4 waves; wave w owns 16 output rows.
// Outputs: K,Q as [b][h][n][64c]  (transposed, feeds QK^T A/B frags)
//          V   as [b][h][64c][n]  (feeds PV A frags)
// ---------------------------------------------------------------------------
__global__ __launch_bounds__(256) void proj_qkv_mfma(
    const float* __restrict__ wk, const float* __restrict__ bk,
    const float* __restrict__ wq, const float* __restrict__ bq,
    const float* __restrict__ wv, const float* __restrict__ bv,
    const f16* __restrict__ Xt,
    f16* __restrict__ Kt, f16* __restrict__ Qt, f16* __restrict__ Vg)
{
    const int t = threadIdx.x, l = t & 63, w = t >> 6;
    const int lm = l & 15, lg = l >> 4;
    const int n0 = blockIdx.x * 64;
    const int sel = blockIdx.y >> 2, h = blockIdx.y & 3;
    const int b = blockIdx.z;
    const int o0 = h * 64;

    const float* W  = sel == 0 ? wk : (sel == 1 ? wq : wv);
    const float* Bi = sel == 0 ? bk : (sel == 1 ? bq : bv);

    f32x4 acc[4] = {{0.f,0.f,0.f,0.f},{0.f,0.f,0.f,0.f},
                    {0.f,0.f,0.f,0.f},{0.f,0.f,0.f,0.f}};
    const int o_row = o0 + w * 16 + lm;   // A-frag row (lane&15)

#pragma unroll
    for (int ks = 0; ks < 8; ++ks) {
        const float* wp = &W[(size_t)o_row * CH + ks * 32 + lg * 8];
        const float4 wa = *reinterpret_cast<const float4*>(wp);
        const float4 wb = *reinterpret_cast<const float4*>(wp + 4);
        const f16x8 a = {(f16)wa.x, (f16)wa.y, (f16)wa.z, (f16)wa.w,
                         (f16)wb.x, (f16)wb.y, (f16)wb.z, (f16)wb.w};
#pragma unroll
        for (int nt = 0; nt < 4; ++nt) {
            const f16x8 bf = *reinterpret_cast<const f16x8*>(
                &Xt[((size_t)(b * NT + n0 + nt * 16 + lm)) * CH + ks * 32 + lg * 8]);
            acc[nt] = MFMA16(a, bf, acc[nt]);
        }
    }

    // D: col = lane&15 = n, row = o0 + w*16 + lg*4 + r
    const int c_base = w * 16 + lg * 4;
    const float4 bias4 = *reinterpret_cast<const float4*>(&Bi[o0 + c_base]);
    const float bb[4] = {bias4.x, bias4.y, bias4.z, bias4.w};

    if (sel < 2) {
        f16* Out = sel == 0 ? Kt : Qt;
#pragma unroll
        for (int nt = 0; nt < 4; ++nt) {
            const int n = n0 + nt * 16 + lm;
            f16x4 o = {(f16)(acc[nt][0] + bb[0]), (f16)(acc[nt][1] + bb[1]),
                       (f16)(acc[nt][2] + bb[2]), (f16)(acc[nt][3] + bb[3])};
            *reinterpret_cast<f16x4*>(
                &Out[((size_t)((b * NHEADS + h) * NT + n)) * HC + c_base]) = o;
        }
    } else {
#pragma unroll
        for (int nt = 0; nt < 4; ++nt) {
            const int n = n0 + nt * 16 + lm;
#pragma unroll
            for (int r = 0; r < 4; ++r)
                Vg[((size_t)((b * NHEADS + h) * HC + c_base + r)) * NT + n] =
                    (f16)(acc[nt][r] + bb[r]);
        }
    }
}

// ---------------------------------------------------------------------------
// Flash attention, MFMA f16, softmax over keys.
// grid (36, 4, 4) = (qtile 64, head, batch), block 256 = 4 waves.
// Wave w owns 16 queries. Zero __syncthreads: per-wave LDS P buffer only.
//   S = K^T Q  (A = K^T from Kt[b][h][n][c], B = Q from Qt[b][h][n][c])
//   in-register online softmax (C col = lane&15 = query; reduce via shfl ±16/±32)
//   O = V P    (A = V from Vg[b][h][c][n], B = P via per-wave LDS)
// Output Ot[b][n][256o] f16 (transposed, feeds final GEMM B-frags).
// ---------------------------------------------------------------------------
__global__ __launch_bounds__(256) void attn_mfma_f16(
    const f16* __restrict__ Kt, const f16* __restrict__ Qt,
    const f16* __restrict__ Vg, f16* __restrict__ Ot)
{
    __shared__ f16 Pt[4][16][72];   // per-wave [query m][key n], pad 72
    const int t = threadIdx.x, l = t & 63, w = t >> 6;
    const int lm = l & 15, lg = l >> 4;
    const int m0 = blockIdx.x * 64, h = blockIdx.y, b = blockIdx.z;
    const size_t bh = (size_t)(b * NHEADS + h);
    const f16* Kb = Kt + bh * NT * HC;
    const f16* Qb = Qt + bh * NT * HC;
    const f16* Vb = Vg + bh * HC * NT;

    const int mq = m0 + w * 16 + lm;   // this lane's query column
    f16x8 qf[2];
#pragma unroll
    for (int ks = 0; ks < 2; ++ks)
        qf[ks] = *reinterpret_cast<const f16x8*>(
            &Qb[(size_t)mq * HC + ks * 32 + lg * 8]);

    f32x4 acc[4] = {{0.f,0.f,0.f,0.f},{0.f,0.f,0.f,0.f},
                    {0.f,0.f,0.f,0.f},{0.f,0.f,0.f,0.f}};
    float m_run = -3.0e38f, l_run = 0.0f;

    for (int kc = 0; kc < NT; kc += 64) {
        // ---- QK^T: lane holds S[n in 16 vals][m = mq] -------------------
        f32x4 s[4];
#pragma unroll
        for (int nt = 0; nt < 4; ++nt) {
            const f16* kp = &Kb[(size_t)(kc + nt * 16 + lm) * HC + lg * 8];
            const f16x8 k0 = *reinterpret_cast<const f16x8*>(kp);
            const f16x8 k1 = *reinterpret_cast<const f16x8*>(kp + 32);
            f32x4 z = {0.f, 0.f, 0.f, 0.f};
            z = MFMA16(k0, qf[0], z);
            s[nt] = MFMA16(k1, qf[1], z);
        }
        // ---- online softmax (per query mq) ------------------------------
        float cm = -3.0e38f;
#pragma unroll
        for (int nt = 0; nt < 4; ++nt)
#pragma unroll
            for (int r = 0; r < 4; ++r) cm = fmaxf(cm, s[nt][r]);
        cm = fmaxf(cm, __shfl_xor(cm, 16));
        cm = fmaxf(cm, __shfl_xor(cm, 32));
        const float mNew = fmaxf(m_run, cm);
        const float fac = __expf(m_run - mNew);
        float psum = 0.0f;
#pragma unroll
        for (int nt = 0; nt < 4; ++nt)
#pragma unroll
            for (int r = 0; r < 4; ++r) {
                const float p = __expf(s[nt][r] - mNew);
                s[nt][r] = p;
                psum += p;
            }
        psum += __shfl_xor(psum, 16);
        psum += __shfl_xor(psum, 32);
        l_run = l_run * fac + psum;
        m_run = mNew;

        // ---- P -> per-wave LDS (B-frag layout), same-wave only ----------
#pragma unroll
        for (int nt = 0; nt < 4; ++nt) {
            f16x4 pv = {(f16)s[nt][0], (f16)s[nt][1],
                        (f16)s[nt][2], (f16)s[nt][3]};
            *reinterpret_cast<f16x4*>(&Pt[w][lm][nt * 16 + lg * 4]) = pv;
        }
        asm volatile("s_waitcnt lgkmcnt(0)" ::: "memory");

        // ---- rescale acc, then O += V @ P -------------------------------
#pragma unroll
        for (int ct = 0; ct < 4; ++ct) {
            acc[ct][0] *= fac; acc[ct][1] *= fac;
            acc[ct][2] *= fac; acc[ct][3] *= fac;
        }
        const f16x8 pb0 = *reinterpret_cast<const f16x8*>(&Pt[w][lm][lg * 8]);
        const f16x8 pb1 = *reinterpret_cast<const f16x8*>(&Pt[w][lm][32 + lg * 8]);
#pragma unroll
        for (int ct = 0; ct < 4; ++ct) {
            const f16* vp = &Vb[(size_t)(ct * 16 + lm) * NT + kc + lg * 8];
            const f16x8 v0 = *reinterpret_cast<const f16x8*>(vp);
            const f16x8 v1 = *reinterpret_cast<const f16x8*>(vp + 32);
            acc[ct] = MFMA16(v0, pb0, acc[ct]);
            acc[ct] = MFMA16(v1, pb1, acc[ct]);
        }
    }

    // ---- epilogue: /= denom, store Ot[b][n=mq][h*64 + c] -----------------
    const float inv = 1.0f / l_run;
#pragma unroll
    for (int ct = 0; ct < 4; ++ct) {
        f16x4 o = {(f16)(acc[ct][0] * inv), (f16)(acc[ct][1] * inv),
                   (f16)(acc[ct][2] * inv), (f16)(acc[ct][3] * inv)};
        *reinterpret_cast<f16x4*>(
            &Ot[((size_t)(b * NT + mq)) * CH + h * HC + ct * 16 + lg * 4]) = o;
    }
}

// ---------------------------------------------------------------------------
// Final conv1x1: out[b][o][n] f32 = wo @ O + bo.  B-frags from Ot[b][n][c].
// grid (36, 4, 4) = (ntile, otile, b), block 256.
// ---------------------------------------------------------------------------
__global__ __launch_bounds__(256) void out_gemm_mfma(
    const float* __restrict__ wo, const float* __restrict__ bo,
    const f16* __restrict__ Ot, float* __restrict__ Y)
{
    const int t = threadIdx.x, l = t & 63, w = t >> 6;
    const int lm = l & 15, lg = l >> 4;
    const int n0 = blockIdx.x * 64;
    const int o0 = blockIdx.y * 64;
    const int b = blockIdx.z;

    f32x4 acc[4] = {{0.f,0.f,0.f,0.f},{0.f,0.f,0.f,0.f},
                    {0.f,0.f,0.f,0.f},{0.f,0.f,0.f,0.f}};
    const int o_row = o0 + w * 16 + lm;

#pragma unroll
    for (int ks = 0; ks < 8; ++ks) {
        const float* wp = &wo[(size_t)o_row * CH + ks * 32 + lg * 8];
        const float4 wa = *reinterpret_cast<const float4*>(wp);
        const float4 wb = *reinterpret_cast<const float4*>(wp + 4);
        const f16x8 a = {(f16)wa.x, (f16)wa.y, (f16)wa.z, (f16)wa.w,
                         (f16)wb.x, (f16)wb.y, (f16)wb.z, (f16)wb.w};
#pragma unroll
        for (int nt = 0; nt < 4; ++nt) {
            const f16x8 bf = *reinterpret_cast<const f16x8*>(
                &Ot[((size_t)(b * NT + n0 + nt * 16 + lm)) * CH + ks * 32 + lg * 8]);
            acc[nt] = MFMA16(a, bf, acc[nt]);
        }
    }

    const int ob = o0 + w * 16 + lg * 4;
    const float4 bias4 = *reinterpret_cast<const float4*>(&bo[ob]);
    const float bb[4] = {bias4.x, bias4.y, bias4.z, bias4.w};
#pragma unroll
    for (int nt = 0; nt < 4; ++nt) {
        const int n = n0 + nt * 16 + lm;
#pragma unroll
        for (int r = 0; r < 4; ++r)
            Y[((size_t)(b * CH + ob + r)) * NT + n] = acc[nt][r] + bb[r];
    }
}

// ---------------------------------------------------------------------------
extern "C" void kernel_launch(void* const* d_in, const int* in_sizes, int n_in,
                              void* d_out, int out_size, void* d_ws, size_t ws_size,
                              hipStream_t stream) {
    (void)in_sizes; (void)n_in; (void)out_size; (void)ws_size;
    const float* x  = (const float*)d_in[0];
    const float* wk = (const float*)d_in[1];
    const float* bk = (const float*)d_in[2];
    const float* wq = (const float*)d_in[3];
    const float* bq = (const float*)d_in[4];
    const float* wv = (const float*)d_in[5];
    const float* bv = (const float*)d_in[6];
    const float* wo = (const float*)d_in[7];
    const float* bo = (const float*)d_in[8];
    float* out = (float*)d_out;

    const size_t SZ = (size_t)NB * NT * CH;   // halves per tensor (2,359,296)
    f16* Xt = (f16*)d_ws;        // [b][n][c]
    f16* Kt = Xt + SZ;           // [b][h][n][c]
    f16* Qt = Kt + SZ;           // [b][h][n][c]
    f16* Vg = Qt + SZ;           // [b][h][c][n]
    f16* Ot = Vg + SZ;           // [b][n][c]      total ~23.6 MB

    xpose_f32_to_f16<<<dim3(36, 4, 4), 256, 0, stream>>>(x, Xt);
    proj_qkv_mfma<<<dim3(36, 12, 4), 256, 0, stream>>>(
        wk, bk, wq, bq, wv, bv, Xt, Kt, Qt, Vg);
    attn_mfma_f16<<<dim3(36, 4, 4), 256, 0, stream>>>(Kt, Qt, Vg, Ot);
    out_gemm_mfma<<<dim3(36, 4, 4), 256, 0, stream>>>(wo, bo, Ot, out);
}

// Round 4
// 215.660 us; speedup vs baseline: 3.2844x; 1.2063x over previous
//
#include <hip/hip_runtime.h>
#include <math.h>

#define NB 4
#define CH 256
#define NHEADS 4
#define HC 64
#define NT 2304   // 48*48
#define KSEG 576  // keys per wave segment (NT/4)

typedef _Float16 f16;
typedef _Float16 f16x4 __attribute__((ext_vector_type(4)));
typedef _Float16 f16x8 __attribute__((ext_vector_type(8)));
typedef float f32x4 __attribute__((ext_vector_type(4)));

#define MFMA16(a, b, c) __builtin_amdgcn_mfma_f32_16x16x32_f16(a, b, c, 0, 0, 0)

// ---------------------------------------------------------------------------
// x [b][c][n] f32  ->  Xt [b][n][c] f16   (so GEMM B-frags read contiguous c)
// grid (36, 4, 4) = (ntile, ctile, b), block 256.
// ---------------------------------------------------------------------------
__global__ __launch_bounds__(256) void xpose_f32_to_f16(
    const float* __restrict__ X, f16* __restrict__ Xt)
{
    __shared__ f16 T[64][68];   // [c][n], pad 68 halves
    const int t = threadIdx.x;
    const int n0 = blockIdx.x * 64, c0 = blockIdx.y * 64, b = blockIdx.z;

#pragma unroll
    for (int i = 0; i < 4; ++i) {
        const int lin = i * 256 + t;
        const int c = lin >> 4, n4 = (lin & 15) << 2;
        const float4 v = *reinterpret_cast<const float4*>(
            &X[((size_t)(b * CH + c0 + c)) * NT + n0 + n4]);
        f16x4 hv = {(f16)v.x, (f16)v.y, (f16)v.z, (f16)v.w};
        *reinterpret_cast<f16x4*>(&T[c][n4]) = hv;
    }
    __syncthreads();
    {
        const int n = t >> 2, cs = (t & 3) << 4;
        f16x8 o0, o1;
#pragma unroll
        for (int k = 0; k < 8; ++k) o0[k] = T[cs + k][n];
#pragma unroll
        for (int k = 0; k < 8; ++k) o1[k] = T[cs + 8 + k][n];
        f16* dst = &Xt[((size_t)(b * NT + n0 + n)) * CH + c0 + cs];
        *reinterpret_cast<f16x8*>(dst) = o0;
        *reinterpret_cast<f16x8*>(dst + 8) = o1;
    }
}

// ---------------------------------------------------------------------------
// Fused K/Q/V projection, MFMA f16.  Y = W @ X + bias.
// grid (36, 12, 4). Outputs: K,Q as [b][h][n][64c]; V as [b][h][64c][n].
// ---------------------------------------------------------------------------
__global__ __launch_bounds__(256) void proj_qkv_mfma(
    const float* __restrict__ wk, const float* __restrict__ bk,
    const float* __restrict__ wq, const float* __restrict__ bq,
    const float* __restrict__ wv, const float* __restrict__ bv,
    const f16* __restrict__ Xt,
    f16* __restrict__ Kt, f16* __restrict__ Qt, f16* __restrict__ Vg)
{
    const int t = threadIdx.x, l = t & 63, w = t >> 6;
    const int lm = l & 15, lg = l >> 4;
    const int n0 = blockIdx.x * 64;
    const int sel = blockIdx.y >> 2, h = blockIdx.y & 3;
    const int b = blockIdx.z;
    const int o0 = h * 64;

    const float* W  = sel == 0 ? wk : (sel == 1 ? wq : wv);
    const float* Bi = sel == 0 ? bk : (sel == 1 ? bq : bv);

    f32x4 acc[4] = {{0.f,0.f,0.f,0.f},{0.f,0.f,0.f,0.f},
                    {0.f,0.f,0.f,0.f},{0.f,0.f,0.f,0.f}};
    const int o_row = o0 + w * 16 + lm;

#pragma unroll
    for (int ks = 0; ks < 8; ++ks) {
        const float* wp = &W[(size_t)o_row * CH + ks * 32 + lg * 8];
        const float4 wa = *reinterpret_cast<const float4*>(wp);
        const float4 wb = *reinterpret_cast<const float4*>(wp + 4);
        const f16x8 a = {(f16)wa.x, (f16)wa.y, (f16)wa.z, (f16)wa.w,
                         (f16)wb.x, (f16)wb.y, (f16)wb.z, (f16)wb.w};
#pragma unroll
        for (int nt = 0; nt < 4; ++nt) {
            const f16x8 bf = *reinterpret_cast<const f16x8*>(
                &Xt[((size_t)(b * NT + n0 + nt * 16 + lm)) * CH + ks * 32 + lg * 8]);
            acc[nt] = MFMA16(a, bf, acc[nt]);
        }
    }

    const int c_base = w * 16 + lg * 4;
    const float4 bias4 = *reinterpret_cast<const float4*>(&Bi[o0 + c_base]);
    const float bb[4] = {bias4.x, bias4.y, bias4.z, bias4.w};

    if (sel < 2) {
        f16* Out = sel == 0 ? Kt : Qt;
#pragma unroll
        for (int nt = 0; nt < 4; ++nt) {
            const int n = n0 + nt * 16 + lm;
            f16x4 o = {(f16)(acc[nt][0] + bb[0]), (f16)(acc[nt][1] + bb[1]),
                       (f16)(acc[nt][2] + bb[2]), (f16)(acc[nt][3] + bb[3])};
            *reinterpret_cast<f16x4*>(
                &Out[((size_t)((b * NHEADS + h) * NT + n)) * HC + c_base]) = o;
        }
    } else {
#pragma unroll
        for (int nt = 0; nt < 4; ++nt) {
            const int n = n0 + nt * 16 + lm;
#pragma unroll
            for (int r = 0; r < 4; ++r)
                Vg[((size_t)((b * NHEADS + h) * HC + c_base + r)) * NT + n] =
                    (f16)(acc[nt][r] + bb[r]);
        }
    }
}

// ---------------------------------------------------------------------------
// Flash attention, split-K across waves (flash-decoding style).
// grid (144, 4, 4) = (16-query tile, head, batch), block 256 = 4 waves.
// Wave w handles keys [w*576, (w+1)*576) for the block's 16 queries, keeping
// partial (m, l, acc) in registers; block-level merge via LDS at the end.
// V loads issued before softmax so their latency hides under it.
// ---------------------------------------------------------------------------
__global__ __launch_bounds__(256, 4) void attn_mfma_f16_split(
    const f16* __restrict__ Kt, const f16* __restrict__ Qt,
    const f16* __restrict__ Vg, f16* __restrict__ Ot)
{
    __shared__ f16 Pt[4][16][72];        // per-wave P staging [query][key]
    __shared__ float CAcc[4][16][68];    // partial O: [seg][query][channel]
    __shared__ float Cm[4][16], Cl[4][16];

    const int t = threadIdx.x, l = t & 63, w = t >> 6;
    const int lm = l & 15, lg = l >> 4;
    const int m0 = blockIdx.x * 16, h = blockIdx.y, b = blockIdx.z;
    const size_t bh = (size_t)(b * NHEADS + h);
    const f16* Kb = Kt + bh * NT * HC;
    const f16* Qb = Qt + bh * NT * HC;
    const f16* Vb = Vg + bh * HC * NT;

    const int mq = m0 + lm;              // this lane's query
    const f16* qp = &Qb[(size_t)mq * HC + lg * 8];
    const f16x8 qf0 = *reinterpret_cast<const f16x8*>(qp);
    const f16x8 qf1 = *reinterpret_cast<const f16x8*>(qp + 32);

    f32x4 acc[4] = {{0.f,0.f,0.f,0.f},{0.f,0.f,0.f,0.f},
                    {0.f,0.f,0.f,0.f},{0.f,0.f,0.f,0.f}};
    float m_run = -3.0e38f, l_run = 0.0f;

    const int k_begin = w * KSEG;
#pragma unroll 1
    for (int i = 0; i < KSEG / 64; ++i) {
        const int kc = k_begin + i * 64;

        // ---- QK^T: lane holds S[16 keys][query mq] ----------------------
        f32x4 s[4];
#pragma unroll
        for (int nt = 0; nt < 4; ++nt) {
            const f16* kp = &Kb[(size_t)(kc + nt * 16 + lm) * HC + lg * 8];
            const f16x8 k0 = *reinterpret_cast<const f16x8*>(kp);
            const f16x8 k1 = *reinterpret_cast<const f16x8*>(kp + 32);
            f32x4 z = {0.f, 0.f, 0.f, 0.f};
            z = MFMA16(k0, qf0, z);
            s[nt] = MFMA16(k1, qf1, z);
        }

        // ---- issue V loads now; latency hides under softmax -------------
        f16x8 v0[4], v1[4];
#pragma unroll
        for (int ct = 0; ct < 4; ++ct) {
            const f16* vp = &Vb[(size_t)(ct * 16 + lm) * NT + kc + lg * 8];
            v0[ct] = *reinterpret_cast<const f16x8*>(vp);
            v1[ct] = *reinterpret_cast<const f16x8*>(vp + 32);
        }

        // ---- online softmax (per query mq) ------------------------------
        float cm = -3.0e38f;
#pragma unroll
        for (int nt = 0; nt < 4; ++nt)
#pragma unroll
            for (int r = 0; r < 4; ++r) cm = fmaxf(cm, s[nt][r]);
        cm = fmaxf(cm, __shfl_xor(cm, 16));
        cm = fmaxf(cm, __shfl_xor(cm, 32));
        const float mNew = fmaxf(m_run, cm);
        const float fac = __expf(m_run - mNew);
        float psum = 0.0f;
#pragma unroll
        for (int nt = 0; nt < 4; ++nt)
#pragma unroll
            for (int r = 0; r < 4; ++r) {
                const float p = __expf(s[nt][r] - mNew);
                s[nt][r] = p;
                psum += p;
            }
        psum += __shfl_xor(psum, 16);
        psum += __shfl_xor(psum, 32);
        l_run = l_run * fac + psum;
        m_run = mNew;

        // ---- P -> per-wave LDS (B-frag layout), same-wave only ----------
#pragma unroll
        for (int nt = 0; nt < 4; ++nt) {
            f16x4 pv = {(f16)s[nt][0], (f16)s[nt][1],
                        (f16)s[nt][2], (f16)s[nt][3]};
            *reinterpret_cast<f16x4*>(&Pt[w][lm][nt * 16 + lg * 4]) = pv;
        }
        const f16x8 pb0 = *reinterpret_cast<const f16x8*>(&Pt[w][lm][lg * 8]);
        const f16x8 pb1 = *reinterpret_cast<const f16x8*>(&Pt[w][lm][32 + lg * 8]);

        // ---- rescale acc, then O += V @ P -------------------------------
#pragma unroll
        for (int ct = 0; ct < 4; ++ct) {
            acc[ct][0] *= fac; acc[ct][1] *= fac;
            acc[ct][2] *= fac; acc[ct][3] *= fac;
        }
#pragma unroll
        for (int ct = 0; ct < 4; ++ct) {
            acc[ct] = MFMA16(v0[ct], pb0, acc[ct]);
            acc[ct] = MFMA16(v1[ct], pb1, acc[ct]);
        }
    }

    // ---- publish per-wave partials --------------------------------------
#pragma unroll
    for (int ct = 0; ct < 4; ++ct)
        *reinterpret_cast<f32x4*>(&CAcc[w][lm][ct * 16 + lg * 4]) = acc[ct];
    if (lg == 0) { Cm[w][lm] = m_run; Cl[w][lm] = l_run; }
    __syncthreads();

    // ---- merge 4 segments; thread t owns (query q, channels c4..c4+3) ---
    {
        const int q = t >> 4, c4 = (t & 15) << 2;
        const float mA = Cm[0][q], mB = Cm[1][q], mC = Cm[2][q], mD = Cm[3][q];
        const float ms = fmaxf(fmaxf(mA, mB), fmaxf(mC, mD));
        const float wA = __expf(mA - ms), wB = __expf(mB - ms);
        const float wC = __expf(mC - ms), wD = __expf(mD - ms);
        const float lt = wA * Cl[0][q] + wB * Cl[1][q]
                       + wC * Cl[2][q] + wD * Cl[3][q];
        const float inv = 1.0f / lt;
        const f32x4 a0 = *reinterpret_cast<const f32x4*>(&CAcc[0][q][c4]);
        const f32x4 a1 = *reinterpret_cast<const f32x4*>(&CAcc[1][q][c4]);
        const f32x4 a2 = *reinterpret_cast<const f32x4*>(&CAcc[2][q][c4]);
        const f32x4 a3 = *reinterpret_cast<const f32x4*>(&CAcc[3][q][c4]);
        f32x4 o;
#pragma unroll
        for (int r = 0; r < 4; ++r)
            o[r] = (a0[r] * wA + a1[r] * wB + a2[r] * wC + a3[r] * wD) * inv;
        f16x4 oh = {(f16)o[0], (f16)o[1], (f16)o[2], (f16)o[3]};
        *reinterpret_cast<f16x4*>(
            &Ot[((size_t)(b * NT + m0 + q)) * CH + h * HC + c4]) = oh;
    }
}

// ---------------------------------------------------------------------------
// Final conv1x1: out[b][o][n] f32 = wo @ O + bo.  B-frags from Ot[b][n][c].
// grid (36, 4, 4), block 256.
// ---------------------------------------------------------------------------
__global__ __launch_bounds__(256) void out_gemm_mfma(
    const float* __restrict__ wo, const float* __restrict__ bo,
    const f16* __restrict__ Ot, float* __restrict__ Y)
{
    const int t = threadIdx.x, l = t & 63, w = t >> 6;
    const int lm = l & 15, lg = l >> 4;
    const int n0 = blockIdx.x * 64;
    const int o0 = blockIdx.y * 64;
    const int b = blockIdx.z;

    f32x4 acc[4] = {{0.f,0.f,0.f,0.f},{0.f,0.f,0.f,0.f},
                    {0.f,0.f,0.f,0.f},{0.f,0.f,0.f,0.f}};
    const int o_row = o0 + w * 16 + lm;

#pragma unroll
    for (int ks = 0; ks < 8; ++ks) {
        const float* wp = &wo[(size_t)o_row * CH + ks * 32 + lg * 8];
        const float4 wa = *reinterpret_cast<const float4*>(wp);
        const float4 wb = *reinterpret_cast<const float4*>(wp + 4);
        const f16x8 a = {(f16)wa.x, (f16)wa.y, (f16)wa.z, (f16)wa.w,
                         (f16)wb.x, (f16)wb.y, (f16)wb.z, (f16)wb.w};
#pragma unroll
        for (int nt = 0; nt < 4; ++nt) {
            const f16x8 bf = *reinterpret_cast<const f16x8*>(
                &Ot[((size_t)(b * NT + n0 + nt * 16 + lm)) * CH + ks * 32 + lg * 8]);
            acc[nt] = MFMA16(a, bf, acc[nt]);
        }
    }

    const int ob = o0 + w * 16 + lg * 4;
    const float4 bias4 = *reinterpret_cast<const float4*>(&bo[ob]);
    const float bb[4] = {bias4.x, bias4.y, bias4.z, bias4.w};
#pragma unroll
    for (int nt = 0; nt < 4; ++nt) {
        const int n = n0 + nt * 16 + lm;
#pragma unroll
        for (int r = 0; r < 4; ++r)
            Y[((size_t)(b * CH + ob + r)) * NT + n] = acc[nt][r] + bb[r];
    }
}

// ---------------------------------------------------------------------------
extern "C" void kernel_launch(void* const* d_in, const int* in_sizes, int n_in,
                              void* d_out, int out_size, void* d_ws, size_t ws_size,
                              hipStream_t stream) {
    (void)in_sizes; (void)n_in; (void)out_size; (void)ws_size;
    const float* x  = (const float*)d_in[0];
    const float* wk = (const float*)d_in[1];
    const float* bk = (const float*)d_in[2];
    const float* wq = (const float*)d_in[3];
    const float* bq = (const float*)d_in[4];
    const float* wv = (const float*)d_in[5];
    const float* bv = (const float*)d_in[6];
    const float* wo = (const float*)d_in[7];
    const float* bo = (const float*)d_in[8];
    float* out = (float*)d_out;

    const size_t SZ = (size_t)NB * NT * CH;   // halves per tensor
    f16* Xt = (f16*)d_ws;        // [b][n][c]
    f16* Kt = Xt + SZ;           // [b][h][n][c]
    f16* Qt = Kt + SZ;           // [b][h][n][c]
    f16* Vg = Qt + SZ;           // [b][h][c][n]
    f16* Ot = Vg + SZ;           // [b][n][c]

    xpose_f32_to_f16<<<dim3(36, 4, 4), 256, 0, stream>>>(x, Xt);
    proj_qkv_mfma<<<dim3(36, 12, 4), 256, 0, stream>>>(
        wk, bk, wq, bq, wv, bv, Xt, Kt, Qt, Vg);
    attn_mfma_f16_split<<<dim3(144, 4, 4), 256, 0, stream>>>(Kt, Qt, Vg, Ot);
    out_gemm_mfma<<<dim3(36, 4, 4), 256, 0, stream>>>(wo, bo, Ot, out);
}

// Round 5
// 114.245 us; speedup vs baseline: 6.1999x; 1.8877x over previous
//
#include <hip/hip_runtime.h>
#include <math.h>

#define NB 4
#define CH 256
#define NHEADS 4
#define HC 64
#define NT 2304   // 48*48
#define NCH 36    // key chunks of 64

typedef _Float16 f16;
typedef _Float16 f16x4 __attribute__((ext_vector_type(4)));
typedef _Float16 f16x8 __attribute__((ext_vector_type(8)));
typedef float f32x4 __attribute__((ext_vector_type(4)));

#define MFMA16(a, b, c) __builtin_amdgcn_mfma_f32_16x16x32_f16(a, b, c, 0, 0, 0)

__device__ __forceinline__ void gload_lds16(const void* g, void* l) {
    __builtin_amdgcn_global_load_lds(
        (const __attribute__((address_space(1))) unsigned int*)g,
        (__attribute__((address_space(3))) unsigned int*)l, 16, 0, 0);
}

// ---------------------------------------------------------------------------
// x [b][c][n] f32  ->  Xt [b][n][c] f16
// grid (36, 4, 4) = (ntile, ctile, b), block 256.
// ---------------------------------------------------------------------------
__global__ __launch_bounds__(256) void xpose_f32_to_f16(
    const float* __restrict__ X, f16* __restrict__ Xt)
{
    __shared__ f16 T[64][68];
    const int t = threadIdx.x;
    const int n0 = blockIdx.x * 64, c0 = blockIdx.y * 64, b = blockIdx.z;

#pragma unroll
    for (int i = 0; i < 4; ++i) {
        const int lin = i * 256 + t;
        const int c = lin >> 4, n4 = (lin & 15) << 2;
        const float4 v = *reinterpret_cast<const float4*>(
            &X[((size_t)(b * CH + c0 + c)) * NT + n0 + n4]);
        f16x4 hv = {(f16)v.x, (f16)v.y, (f16)v.z, (f16)v.w};
        *reinterpret_cast<f16x4*>(&T[c][n4]) = hv;
    }
    __syncthreads();
    {
        const int n = t >> 2, cs = (t & 3) << 4;
        f16x8 o0, o1;
#pragma unroll
        for (int k = 0; k < 8; ++k) o0[k] = T[cs + k][n];
#pragma unroll
        for (int k = 0; k < 8; ++k) o1[k] = T[cs + 8 + k][n];
        f16* dst = &Xt[((size_t)(b * NT + n0 + n)) * CH + c0 + cs];
        *reinterpret_cast<f16x8*>(dst) = o0;
        *reinterpret_cast<f16x8*>(dst + 8) = o1;
    }
}

// ---------------------------------------------------------------------------
// Fused K/Q/V projection, MFMA f16.  Y = W @ X + bias.
// grid (36, 3, 4) = (ntile, sel, b). Each block computes ALL 4 head-tiles
// per Xt read (4x read reuse vs one-tile-per-block).
// Outputs: K,Q as [b][h][n][64c]; V as [b][h][64c][n].
// ---------------------------------------------------------------------------
__global__ __launch_bounds__(256) void proj_qkv_mfma(
    const float* __restrict__ wk, const float* __restrict__ bk,
    const float* __restrict__ wq, const float* __restrict__ bq,
    const float* __restrict__ wv, const float* __restrict__ bv,
    const f16* __restrict__ Xt,
    f16* __restrict__ Kt, f16* __restrict__ Qt, f16* __restrict__ Vg)
{
    const int t = threadIdx.x, l = t & 63, w = t >> 6;
    const int lm = l & 15, lg = l >> 4;
    const int n0 = blockIdx.x * 64;
    const int sel = blockIdx.y;
    const int b = blockIdx.z;

    const float* W  = sel == 0 ? wk : (sel == 1 ? wq : wv);
    const float* Bi = sel == 0 ? bk : (sel == 1 ? bq : bv);

    f32x4 acc[4][4] = {};   // [h][nt]

#pragma unroll 2
    for (int ks = 0; ks < 8; ++ks) {
        f16x8 bf[4];
#pragma unroll
        for (int nt = 0; nt < 4; ++nt)
            bf[nt] = *reinterpret_cast<const f16x8*>(
                &Xt[((size_t)(b * NT + n0 + nt * 16 + lm)) * CH + ks * 32 + lg * 8]);
#pragma unroll
        for (int h = 0; h < 4; ++h) {
            const float* wp = &W[(size_t)(h * 64 + w * 16 + lm) * CH + ks * 32 + lg * 8];
            const float4 wa = *reinterpret_cast<const float4*>(wp);
            const float4 wb = *reinterpret_cast<const float4*>(wp + 4);
            const f16x8 a = {(f16)wa.x, (f16)wa.y, (f16)wa.z, (f16)wa.w,
                             (f16)wb.x, (f16)wb.y, (f16)wb.z, (f16)wb.w};
#pragma unroll
            for (int nt = 0; nt < 4; ++nt)
                acc[h][nt] = MFMA16(a, bf[nt], acc[h][nt]);
        }
    }

    const int c_base = w * 16 + lg * 4;
#pragma unroll
    for (int h = 0; h < 4; ++h) {
        const float4 b4 = *reinterpret_cast<const float4*>(&Bi[h * 64 + c_base]);
        const float bb[4] = {b4.x, b4.y, b4.z, b4.w};
        if (sel < 2) {
            f16* Out = sel == 0 ? Kt : Qt;
#pragma unroll
            for (int nt = 0; nt < 4; ++nt) {
                const int n = n0 + nt * 16 + lm;
                f16x4 o = {(f16)(acc[h][nt][0] + bb[0]), (f16)(acc[h][nt][1] + bb[1]),
                           (f16)(acc[h][nt][2] + bb[2]), (f16)(acc[h][nt][3] + bb[3])};
                *reinterpret_cast<f16x4*>(
                    &Out[((size_t)((b * NHEADS + h) * NT + n)) * HC + c_base]) = o;
            }
        } else {
#pragma unroll
            for (int nt = 0; nt < 4; ++nt) {
                const int n = n0 + nt * 16 + lm;
#pragma unroll
                for (int r = 0; r < 4; ++r)
                    Vg[((size_t)((b * NHEADS + h) * HC + c_base + r)) * NT + n] =
                        (f16)(acc[h][nt][r] + bb[r]);
            }
        }
    }
}

// ---------------------------------------------------------------------------
// Flash attention: LDS-staged K/V shared by 4 waves, double-buffered via
// global_load_lds (linear LDS dest + pre-swizzled global source; reads XOR
// the same swizzle -> 2-way max bank conflicts). XCD-aware block decode:
// xcd = bid&7 owns 2 (b,h) pairs -> K/V working set 1.2 MB, L2-resident.
// grid 576 (1-D), block 256 = 4 waves; wave w owns 16 queries, full keys.
// ---------------------------------------------------------------------------
__global__ __launch_bounds__(256, 3) void attn_mfma_staged(
    const f16* __restrict__ Kt, const f16* __restrict__ Qt,
    const f16* __restrict__ Vg, f16* __restrict__ Ot)
{
    __shared__ f16 SMEM[2][2][64 * 64];   // [buf][K/V][row 64c-or-64k x 128B]
    __shared__ f16 Pt[4][16][72];         // per-wave P staging

    const int t = threadIdx.x, l = t & 63, w = t >> 6;
    const int lm = l & 15, lg = l >> 4;
    const int swz = lm & 7;

    const int bid = blockIdx.x;
    const int xcd = bid & 7, idx = bid >> 3;        // 72 blocks per XCD
    const int bh  = 2 * xcd + (idx >= NCH ? 1 : 0); // 2 (b,h) pairs per XCD
    const int qt  = idx >= NCH ? idx - NCH : idx;
    const int b = bh >> 2, h = bh & 3;
    const int m0 = qt * 64;

    const size_t bhs = (size_t)(b * NHEADS + h);
    const f16* Kb = Kt + bhs * NT * HC;   // [n][64c] rows of 128 B
    const f16* Qb = Qt + bhs * NT * HC;
    const f16* Vb = Vg + bhs * HC * NT;   // [c][n]

    // staging lane decomposition: lane l covers (row srow, 16B unit su)
    const int srow = l >> 3;              // 0..7 within an 8-row group
    const int su   = l & 7;
    const int sx   = su ^ srow;           // pre-swizzled source unit

    // resident Q fragments (16 queries per wave)
    const int mq = m0 + w * 16 + lm;
    const f16* qp = &Qb[(size_t)mq * HC + lg * 8];
    const f16x8 qf0 = *reinterpret_cast<const f16x8*>(qp);
    const f16x8 qf1 = *reinterpret_cast<const f16x8*>(qp + 32);

    f32x4 acc[4] = {{0.f,0.f,0.f,0.f},{0.f,0.f,0.f,0.f},
                    {0.f,0.f,0.f,0.f},{0.f,0.f,0.f,0.f}};
    float m_run = -3.0e38f, l_run = 0.0f;

    auto stage = [&](int kc, int bufsel) {
        if (w < 2) {           // waves 0,1: K chunk (64 keys x 128 B, contiguous)
            const char* Ksrc = (const char*)(Kb + (size_t)kc * HC);
            char* Kdst = (char*)&SMEM[bufsel][0][0];
#pragma unroll
            for (int g = 0; g < 4; ++g) {
                const int rb = w * 32 + g * 8;
                gload_lds16(Ksrc + (size_t)(rb + srow) * 128 + (sx << 4),
                            Kdst + rb * 128);
            }
        } else {               // waves 2,3: V chunk (64 c-rows, strided)
            const char* Vsrc = (const char*)Vb + (size_t)kc * 2;
            char* Vdst = (char*)&SMEM[bufsel][1][0];
#pragma unroll
            for (int g = 0; g < 4; ++g) {
                const int cb = (w - 2) * 32 + g * 8;
                gload_lds16(Vsrc + (size_t)(cb + srow) * (NT * 2) + (sx << 4),
                            Vdst + cb * 128);
            }
        }
    };

    stage(0, 0);
    __syncthreads();   // drains vmcnt -> buf0 ready

    for (int i = 0; i < NCH; ++i) {
        const int cur = i & 1;
        if (i + 1 < NCH) stage((i + 1) * 64, cur ^ 1);   // async prefetch

        const char* Ksh = (const char*)&SMEM[cur][0][0];
        const char* Vsh = (const char*)&SMEM[cur][1][0];

        // ---- QK^T: lane holds S[16 keys][query mq] ----------------------
        f32x4 s[4];
#pragma unroll
        for (int nt = 0; nt < 4; ++nt) {
            const char* rp = Ksh + (nt * 16 + lm) * 128;
            const f16x8 k0 = *reinterpret_cast<const f16x8*>(rp + ((lg ^ swz) << 4));
            const f16x8 k1 = *reinterpret_cast<const f16x8*>(rp + (((lg + 4) ^ swz) << 4));
            f32x4 z = {0.f, 0.f, 0.f, 0.f};
            z = MFMA16(k0, qf0, z);
            s[nt] = MFMA16(k1, qf1, z);
        }

        // ---- online softmax (per query mq) ------------------------------
        float cm = -3.0e38f;
#pragma unroll
        for (int nt = 0; nt < 4; ++nt)
#pragma unroll
            for (int r = 0; r < 4; ++r) cm = fmaxf(cm, s[nt][r]);
        cm = fmaxf(cm, __shfl_xor(cm, 16));
        cm = fmaxf(cm, __shfl_xor(cm, 32));
        const float mNew = fmaxf(m_run, cm);
        const float fac = __expf(m_run - mNew);
        float psum = 0.0f;
#pragma unroll
        for (int nt = 0; nt < 4; ++nt)
#pragma unroll
            for (int r = 0; r < 4; ++r) {
                const float p = __expf(s[nt][r] - mNew);
                s[nt][r] = p;
                psum += p;
            }
        psum += __shfl_xor(psum, 16);
        psum += __shfl_xor(psum, 32);
        l_run = l_run * fac + psum;
        m_run = mNew;

        // ---- P -> per-wave LDS (B-frag layout), same-wave only ----------
#pragma unroll
        for (int nt = 0; nt < 4; ++nt) {
            f16x4 pv = {(f16)s[nt][0], (f16)s[nt][1],
                        (f16)s[nt][2], (f16)s[nt][3]};
            *reinterpret_cast<f16x4*>(&Pt[w][lm][nt * 16 + lg * 4]) = pv;
        }
        const f16x8 pb0 = *reinterpret_cast<const f16x8*>(&Pt[w][lm][lg * 8]);
        const f16x8 pb1 = *reinterpret_cast<const f16x8*>(&Pt[w][lm][32 + lg * 8]);

        // ---- rescale acc, then O += V @ P -------------------------------
#pragma unroll
        for (int ct = 0; ct < 4; ++ct) {
            acc[ct][0] *= fac; acc[ct][1] *= fac;
            acc[ct][2] *= fac; acc[ct][3] *= fac;
        }
#pragma unroll
        for (int ct = 0; ct < 4; ++ct) {
            const char* rp = Vsh + (ct * 16 + lm) * 128;
            const f16x8 v0 = *reinterpret_cast<const f16x8*>(rp + ((lg ^ swz) << 4));
            const f16x8 v1 = *reinterpret_cast<const f16x8*>(rp + (((lg + 4) ^ swz) << 4));
            acc[ct] = MFMA16(v0, pb0, acc[ct]);
            acc[ct] = MFMA16(v1, pb1, acc[ct]);
        }

        __syncthreads();   // all waves done with buf[cur]; prefetch drained
    }

    // ---- epilogue: /= denom, store Ot[b][n=mq][h*64 + c] -----------------
    const float inv = 1.0f / l_run;
#pragma unroll
    for (int ct = 0; ct < 4; ++ct) {
        f16x4 oh = {(f16)(acc[ct][0] * inv), (f16)(acc[ct][1] * inv),
                    (f16)(acc[ct][2] * inv), (f16)(acc[ct][3] * inv)};
        *reinterpret_cast<f16x4*>(
            &Ot[((size_t)(b * NT + mq)) * CH + h * HC + ct * 16 + lg * 4]) = oh;
    }
}

// ---------------------------------------------------------------------------
// Final conv1x1: out[b][o][n] f32 = wo @ O + bo.  B-frags from Ot[b][n][c].
// grid (36, 4, 4), block 256.
// ---------------------------------------------------------------------------
__global__ __launch_bounds__(256) void out_gemm_mfma(
    const float* __restrict__ wo, const float* __restrict__ bo,
    const f16* __restrict__ Ot, float* __restrict__ Y)
{
    const int t = threadIdx.x, l = t & 63, w = t >> 6;
    const int lm = l & 15, lg = l >> 4;
    const int n0 = blockIdx.x * 64;
    const int o0 = blockIdx.y * 64;
    const int b = blockIdx.z;

    f32x4 acc[4] = {{0.f,0.f,0.f,0.f},{0.f,0.f,0.f,0.f},
                    {0.f,0.f,0.f,0.f},{0.f,0.f,0.f,0.f}};
    const int o_row = o0 + w * 16 + lm;

#pragma unroll
    for (int ks = 0; ks < 8; ++ks) {
        const float* wp = &wo[(size_t)o_row * CH + ks * 32 + lg * 8];
        const float4 wa = *reinterpret_cast<const float4*>(wp);
        const float4 wb = *reinterpret_cast<const float4*>(wp + 4);
        const f16x8 a = {(f16)wa.x, (f16)wa.y, (f16)wa.z, (f16)wa.w,
                         (f16)wb.x, (f16)wb.y, (f16)wb.z, (f16)wb.w};
#pragma unroll
        for (int nt = 0; nt < 4; ++nt) {
            const f16x8 bf = *reinterpret_cast<const f16x8*>(
                &Ot[((size_t)(b * NT + n0 + nt * 16 + lm)) * CH + ks * 32 + lg * 8]);
            acc[nt] = MFMA16(a, bf, acc[nt]);
        }
    }

    const int ob = o0 + w * 16 + lg * 4;
    const float4 bias4 = *reinterpret_cast<const float4*>(&bo[ob]);
    const float bb[4] = {bias4.x, bias4.y, bias4.z, bias4.w};
#pragma unroll
    for (int nt = 0; nt < 4; ++nt) {
        const int n = n0 + nt * 16 + lm;
#pragma unroll
        for (int r = 0; r < 4; ++r)
            Y[((size_t)(b * CH + ob + r)) * NT + n] = acc[nt][r] + bb[r];
    }
}

// ---------------------------------------------------------------------------
extern "C" void kernel_launch(void* const* d_in, const int* in_sizes, int n_in,
                              void* d_out, int out_size, void* d_ws, size_t ws_size,
                              hipStream_t stream) {
    (void)in_sizes; (void)n_in; (void)out_size; (void)ws_size;
    const float* x  = (const float*)d_in[0];
    const float* wk = (const float*)d_in[1];
    const float* bk = (const float*)d_in[2];
    const float* wq = (const float*)d_in[3];
    const float* bq = (const float*)d_in[4];
    const float* wv = (const float*)d_in[5];
    const float* bv = (const float*)d_in[6];
    const float* wo = (const float*)d_in[7];
    const float* bo = (const float*)d_in[8];
    float* out = (float*)d_out;

    const size_t SZ = (size_t)NB * NT * CH;   // halves per tensor
    f16* Xt = (f16*)d_ws;        // [b][n][c]
    f16* Kt = Xt + SZ;           // [b][h][n][c]
    f16* Qt = Kt + SZ;           // [b][h][n][c]
    f16* Vg = Qt + SZ;           // [b][h][c][n]
    f16* Ot = Vg + SZ;           // [b][n][c]

    xpose_f32_to_f16<<<dim3(36, 4, 4), 256, 0, stream>>>(x, Xt);
    proj_qkv_mfma<<<dim3(36, 3, 4), 256, 0, stream>>>(
        wk, bk, wq, bq, wv, bv, Xt, Kt, Qt, Vg);
    attn_mfma_staged<<<dim3(576), 256, 0, stream>>>(Kt, Qt, Vg, Ot);
    out_gemm_mfma<<<dim3(36, 4, 4), 256, 0, stream>>>(wo, bo, Ot, out);
}